// Round 19
// baseline (126.544 us; speedup 1.0000x reference)
//
#include <hip/hip_runtime.h>
#include <hip/hip_bf16.h>

typedef __attribute__((ext_vector_type(8))) short bf16x8;
typedef __attribute__((ext_vector_type(4))) float f32x4;

constexpr int B   = 2;
constexpr int CIN = 256;
constexpr int CO  = 128;
constexpr int H = 48, W = 48;
constexpr int H2 = 96, W2 = 96;
constexpr int NPIX1 = H * W;    // 2304
constexpr int NPIX2 = H2 * W2;  // 9216
constexpr int NS = 4;           // conv split-K factor

__device__ inline ushort f2bf(float v)
{
  __hip_bfloat16 h = __float2bfloat16(v);
  return *reinterpret_cast<ushort*>(&h);
}

// ---------------- prep: all weight transforms + input/feature NHWC cvt ----------------
__global__ __launch_bounds__(256) void prep_all_kernel(
    const float* __restrict__ pac_w, const float* __restrict__ conv1_w,
    const float* __restrict__ conv2_w, const float* __restrict__ feat_w,
    const float* __restrict__ res_w, const float* __restrict__ input,
    const float* __restrict__ feature,
    ushort* __restrict__ wbb, ushort* __restrict__ wt1, ushort* __restrict__ wt2,
    ushort* __restrict__ fwb, ushort* __restrict__ wrb,
    ushort* __restrict__ xinh, ushort* __restrict__ fh)
{
  __shared__ float lt[32][65];
  int blk = blockIdx.x, tid = threadIdx.x;
  if (blk < 1600) {
    int idx = blk * 256 + tid;
    int c = idx & 127, o = (idx >> 7) & 127, p = idx >> 14;
    wbb[idx] = f2bf(pac_w[((size_t)o * CO + c) * 25 + p]);
  } else if (blk < 2752) {
    int idx = (blk - 1600) * 256 + tid;
    int ci = idx & 255, o = (idx >> 8) & 127, tap = idx >> 15;
    wt1[idx] = f2bf(conv1_w[((size_t)o * CIN + ci) * 9 + tap]);
  } else if (blk < 3328) {
    int idx = (blk - 2752) * 256 + tid;
    int ci = idx & 127, o = (idx >> 7) & 127, tap = idx >> 14;
    wt2[idx] = f2bf(conv2_w[((size_t)o * CO + ci) * 9 + tap]);
  } else if (blk < 3392) {
    int idx = (blk - 3328) * 256 + tid;
    fwb[idx] = f2bf(feat_w[idx]);
  } else if (blk < 3520) {
    int idx = (blk - 3392) * 256 + tid;
    wrb[idx] = f2bf(res_w[idx]);
  } else if (blk < 4096) {
    int b2 = blk - 3520;
    int cg = b2 & 7;
    int pc = (b2 >> 3) % 36;
    int b  = b2 / (8 * 36);
    int c0 = cg * 32, pix0 = pc * 64;
#pragma unroll
    for (int r = 0; r < 8; r++) {
      int c_l = r * 4 + (tid >> 6), px = tid & 63;
      lt[c_l][px] = input[((size_t)b * CIN + c0 + c_l) * NPIX1 + pix0 + px];
    }
    __syncthreads();
    int c_l = tid & 31;
#pragma unroll
    for (int r = 0; r < 8; r++) {
      int px = r * 8 + (tid >> 5);
      xinh[((size_t)b * NPIX1 + pix0 + px) * CIN + c0 + c_l] = f2bf(lt[c_l][px]);
    }
  } else {
    int b2 = blk - 4096;
    int cg = b2 & 3;
    int pc = (b2 >> 2) % 144;
    int b  = b2 / (4 * 144);
    int c0 = cg * 32, pix0 = pc * 64;
#pragma unroll
    for (int r = 0; r < 8; r++) {
      int c_l = r * 4 + (tid >> 6), px = tid & 63;
      lt[c_l][px] = feature[((size_t)b * CO + c0 + c_l) * NPIX2 + pix0 + px];
    }
    __syncthreads();
    int c_l = tid & 31;
#pragma unroll
    for (int r = 0; r < 8; r++) {
      int px = r * 8 + (tid >> 5);
      fh[((size_t)b * NPIX2 + pix0 + px) * CO + c0 + c_l] = f2bf(lt[c_l][px]);
    }
  }
}

// ---------------- conv3x3 MFMA body, split-K (NS) x split-O (2) ----------------
template<int CIg>
__device__ __forceinline__ void conv3_body(
    int blk, int tid, char* smraw,
    const ushort* __restrict__ xh, const ushort* __restrict__ wt,
    float* __restrict__ pout)
{
  constexpr int CS = CIg / NS;
  constexpr int G  = CS / 8;
  constexpr int KC = CS / 32;
  ushort* xt = (ushort*)smraw;
  int tile = blk % 36;
  int s = (blk / 36) & 3;
  int oh = (blk / 144) & 1;
  int b = blk / 288;
  int th = tile / 3, tw = tile % 3;
  int h0 = th * 4, w0 = tw * 16;
  int lane = tid & 63, wv = tid >> 6;
  int l15 = lane & 15, l4 = (lane >> 4) & 3;

  for (int q = tid; q < 108 * G; q += 256) {
    int pixi = q / G, g = q & (G - 1);
    int rh = pixi / 18, rw = pixi - rh * 18;
    int hg = h0 - 1 + rh, wg = w0 - 1 + rw;
    uint4 v{0u, 0u, 0u, 0u};
    if (hg >= 0 && hg < H && wg >= 0 && wg < W)
      v = *(const uint4*)(xh + (size_t)(b * NPIX1 + hg * W + wg) * CIg + s * CS + g * 8);
    *(uint4*)(xt + pixi * CS + ((g ^ (pixi & (G - 1))) * 8)) = v;
  }
  __syncthreads();

  int wo = oh * 64 + wv * 16;
  const ushort* wbase = wt + (size_t)(wo + l15) * CIg + s * CS + l4 * 8;

  f32x4 acc[4];
#pragma unroll
  for (int nf = 0; nf < 4; nf++) acc[nf] = {0.f, 0.f, 0.f, 0.f};

  bf16x8 aC[KC], aN[KC];
#pragma unroll
  for (int kc = 0; kc < KC; kc++)
    aC[kc] = *(const bf16x8*)(wbase + kc * 32);

#pragma unroll 1
  for (int tap = 0; tap < 9; ++tap) {
    if (tap < 8) {
      const ushort* wn = wbase + (size_t)(tap + 1) * 128 * CIg;
#pragma unroll
      for (int kc = 0; kc < KC; kc++)
        aN[kc] = *(const bf16x8*)(wn + kc * 32);
    }
    int kh = (tap >= 6) ? 2 : ((tap >= 3) ? 1 : 0);
    int kw = tap - kh * 3;
#pragma unroll
    for (int kc = 0; kc < KC; kc++) {
#pragma unroll
      for (int nf = 0; nf < 4; nf++) {
        int pix = (nf + kh) * 18 + kw + l15;
        bf16x8 bb = *(const bf16x8*)(xt + pix * CS + (((kc * 4 + l4) ^ (pix & (G - 1))) * 8));
        acc[nf] = __builtin_amdgcn_mfma_f32_16x16x32_bf16(aC[kc], bb, acc[nf], 0, 0, 0);
      }
    }
#pragma unroll
    for (int kc = 0; kc < KC; kc++) aC[kc] = aN[kc];
  }

#pragma unroll
  for (int nf = 0; nf < 4; nf++) {
    int pixg = (h0 + nf) * W + w0 + l15;
#pragma unroll
    for (int r = 0; r < 4; r++) {
      int o = wo + l4 * 4 + r;
      pout[((size_t)(s * B + b) * CO + o) * NPIX1 + pixg] = acc[nf][r];
    }
  }
}

// ---------------- gemm_res body (32 px, CI=256) ----------------
__device__ __forceinline__ void gemm_res_body(
    int blk, int tid, char* smraw,
    const ushort* __restrict__ xh, const ushort* __restrict__ wrb,
    const float* __restrict__ bias, float* __restrict__ out)
{
  ushort* xt = (ushort*)smraw;    // 32*256
  int pc = blk % 72;
  int b  = blk / 72;
  int pix0 = pc * 32;
  int lane = tid & 63, wv = tid >> 6;
  int l15 = lane & 15, l4 = (lane >> 4) & 3;

  for (int q = tid; q < 1024; q += 256) {
    int pixi = q >> 5, g = q & 31;
    uint4 v = *(const uint4*)(xh + (((size_t)b * NPIX1 + pix0 + pixi) << 8) + (g << 3));
    *(uint4*)(xt + (pixi << 8) + ((g ^ (pixi & 31)) << 3)) = v;
  }
  __syncthreads();

  int wo = wv * 32;
  const ushort* wbase = wrb + (size_t)(wo + l15) * CIN + l4 * 8;
  bf16x8 a0[8], a1[8];
#pragma unroll
  for (int kc = 0; kc < 8; kc++) {
    a0[kc] = *(const bf16x8*)(wbase + kc * 32);
    a1[kc] = *(const bf16x8*)(wbase + 16 * CIN + kc * 32);
  }
  f32x4 acc0[2], acc1[2];
#pragma unroll
  for (int nf = 0; nf < 2; nf++) {
    acc0[nf] = {0.f, 0.f, 0.f, 0.f};
    acc1[nf] = {0.f, 0.f, 0.f, 0.f};
  }
#pragma unroll
  for (int nf = 0; nf < 2; nf++) {
    int pix = nf * 16 + l15;
    int base = pix << 8;
    int sw = pix & 31;
#pragma unroll
    for (int kc = 0; kc < 8; kc++) {
      bf16x8 bb = *(const bf16x8*)(xt + base + ((((kc << 2) + l4) ^ sw) << 3));
      acc0[nf] = __builtin_amdgcn_mfma_f32_16x16x32_bf16(a0[kc], bb, acc0[nf], 0, 0, 0);
      acc1[nf] = __builtin_amdgcn_mfma_f32_16x16x32_bf16(a1[kc], bb, acc1[nf], 0, 0, 0);
    }
  }
#pragma unroll
  for (int nf = 0; nf < 2; nf++) {
    int gp = pix0 + nf * 16 + l15;
#pragma unroll
    for (int r = 0; r < 4; r++) {
      int o = wo + l4 * 4 + r;
      out[((size_t)b * CO + o) * NPIX1 + gp] = acc0[nf][r] + bias[o];
      out[((size_t)b * CO + o + 16) * NPIX1 + gp] = acc1[nf][r] + bias[o + 16];
    }
  }
}

// ---------------- gemm1x1 body (64 px, CI=128) ----------------
__device__ __forceinline__ void gemm1x1_body(
    int blk, int tid, char* smraw,
    const ushort* __restrict__ fh, const ushort* __restrict__ fwb,
    const float* __restrict__ bias, float* __restrict__ out)
{
  ushort* xt = (ushort*)smraw;    // 64*128
  int pc = blk % 144;
  int b  = blk / 144;
  int pix0 = pc * 64;
  int lane = tid & 63, wv = tid >> 6;
  int l15 = lane & 15, l4 = (lane >> 4) & 3;

  for (int q = tid; q < 1024; q += 256) {
    int pixi = q >> 4, g = q & 15;
    uint4 v = *(const uint4*)(fh + (((size_t)b * NPIX2 + pix0 + pixi) << 7) + (g << 3));
    *(uint4*)(xt + (pixi << 7) + ((g ^ (pixi & 15)) << 3)) = v;
  }
  __syncthreads();

  int wo = wv * 32;
  const ushort* wbase = fwb + (size_t)(wo + l15) * CO + l4 * 8;
  bf16x8 a0[4], a1[4];
#pragma unroll
  for (int kc = 0; kc < 4; kc++) {
    a0[kc] = *(const bf16x8*)(wbase + kc * 32);
    a1[kc] = *(const bf16x8*)(wbase + 16 * CO + kc * 32);
  }
  f32x4 acc0[4], acc1[4];
#pragma unroll
  for (int nf = 0; nf < 4; nf++) {
    acc0[nf] = {0.f, 0.f, 0.f, 0.f};
    acc1[nf] = {0.f, 0.f, 0.f, 0.f};
  }
#pragma unroll
  for (int nf = 0; nf < 4; nf++) {
    int pix = nf * 16 + l15;
    int base = pix << 7;
    int sw = pix & 15;
#pragma unroll
    for (int kc = 0; kc < 4; kc++) {
      bf16x8 bb = *(const bf16x8*)(xt + base + ((((kc << 2) + l4) ^ sw) << 3));
      acc0[nf] = __builtin_amdgcn_mfma_f32_16x16x32_bf16(a0[kc], bb, acc0[nf], 0, 0, 0);
      acc1[nf] = __builtin_amdgcn_mfma_f32_16x16x32_bf16(a1[kc], bb, acc1[nf], 0, 0, 0);
    }
  }
#pragma unroll
  for (int nf = 0; nf < 4; nf++) {
    int gp = pix0 + nf * 16 + l15;
#pragma unroll
    for (int r = 0; r < 4; r++) {
      int o = wo + l4 * 4 + r;
      out[((size_t)b * CO + o) * NPIX2 + gp] = acc0[nf][r] + bias[o];
      out[((size_t)b * CO + o + 16) * NPIX2 + gp] = acc1[nf][r] + bias[o + 16];
    }
  }
}

// ---------------- MegaA: conv1 (576) | gemm_res (144) | gemm1x1 (288) ----------------
__global__ __launch_bounds__(256, 4) void megaA_kernel(
    const ushort* __restrict__ xinh, const ushort* __restrict__ wt1,
    float* __restrict__ pws,
    const ushort* __restrict__ wrb, const float* __restrict__ res_b,
    float* __restrict__ radd,
    const ushort* __restrict__ fh, const ushort* __restrict__ fwb,
    const float* __restrict__ feat_b, float* __restrict__ g)
{
  __shared__ __align__(16) char sm[16384];
  int blk = blockIdx.x, tid = threadIdx.x;
  if (blk < 576)      conv3_body<CIN>(blk, tid, sm, xinh, wt1, pws);
  else if (blk < 720) gemm_res_body(blk - 576, tid, sm, xinh, wrb, res_b, radd);
  else                gemm1x1_body(blk - 720, tid, sm, fh, fwb, feat_b, g);
}

// ---------------- reduce1 + stats body ----------------
__device__ __forceinline__ void reduce1_body(
    int bc, int tid,
    const float* __restrict__ pout, const float* __restrict__ inw,
    const float* __restrict__ inb, float* __restrict__ scsh,
    float* __restrict__ outred)
{
  int c = bc & 127;
  float s = 0.f, s2 = 0.f;
#pragma unroll
  for (int i = 0; i < 9; i++) {
    size_t base = (size_t)bc * NPIX1 + tid + i * 256;
    float x = pout[base];
#pragma unroll
    for (int k = 1; k < NS; k++) x += pout[(size_t)k * B * CO * NPIX1 + base];
    outred[base] = x;
    s += x; s2 += x * x;
  }
#pragma unroll
  for (int off = 32; off > 0; off >>= 1) {
    s  += __shfl_down(s, off);
    s2 += __shfl_down(s2, off);
  }
  __shared__ float rs[4], rs2[4];
  int wid = tid >> 6, lane = tid & 63;
  if (lane == 0) { rs[wid] = s; rs2[wid] = s2; }
  __syncthreads();
  if (tid == 0) {
    float S  = rs[0] + rs[1] + rs[2] + rs[3];
    float S2 = rs2[0] + rs2[1] + rs2[2] + rs2[3];
    float mean = S * (1.f / NPIX1);
    float var  = S2 * (1.f / NPIX1) - mean * mean;
    float inv  = rsqrtf(var + 1e-5f);
    float sc = inw[c] * inv;
    scsh[2 * bc]     = sc;
    scsh[2 * bc + 1] = inb[c] - mean * sc;
  }
}

// ---------------- PAC guidance d2 partial body (8-ch chunks) ----------------
__device__ __forceinline__ void kern_part_body(
    int blk, int tid, char* smraw,
    const float* __restrict__ g, float* __restrict__ pd2)
{
  float (*gt)[480] = (float(*)[480])smraw;
  int s = blk & 3;
  int tile = (blk >> 2) % 36;
  int b = blk / (4 * 36);
  int ty = tile / 6, tx = tile % 6;
  int h0 = ty * 16, w0 = tx * 16;
  int px = tid & 15, py = tid >> 4;
  float d2[25];
#pragma unroll
  for (int p = 0; p < 25; p++) d2[p] = 0.f;

  int cbase = s * 32;
#pragma unroll 1
  for (int cc = 0; cc < 32; cc += 8) {
    for (int idx = tid; idx < 3200; idx += 256) {
      int c_l = idx / 400, r = idx - c_l * 400;
      int rh = r / 20, rw = r - rh * 20;
      int hh = h0 - 2 + rh, ww = w0 - 2 + rw;
      float v = 0.f;
      if (hh >= 0 && hh < H2 && ww >= 0 && ww < W2)
        v = g[((size_t)b * CO + cbase + cc + c_l) * NPIX2 + hh * W2 + ww];
      gt[c_l][rh * 24 + rw] = v;
    }
    __syncthreads();
#pragma unroll
    for (int c_l = 0; c_l < 8; c_l++) {
      float ctr = gt[c_l][(py + 2) * 24 + px + 2];
#pragma unroll
      for (int dy = 0; dy < 5; dy++)
#pragma unroll
        for (int dx = 0; dx < 5; dx++) {
          float d = gt[c_l][(py + dy) * 24 + px + dx] - ctr;
          d2[dy * 5 + dx] += d * d;
        }
    }
    __syncthreads();
  }
  float* op = pd2 + ((size_t)((b * 36 + tile) * 4 + s) * 25) * 256 + tid;
#pragma unroll
  for (int p = 0; p < 25; p++) op[(size_t)p * 256] = d2[p];
}

// ---------------- MegaB: reduce1 (256) | kern_part (288) ----------------
__global__ __launch_bounds__(256, 4) void megaB_kernel(
    const float* __restrict__ pws, const float* __restrict__ in1_w,
    const float* __restrict__ in1_b, float* __restrict__ scsh,
    float* __restrict__ t2red,
    const float* __restrict__ g, float* __restrict__ pd2)
{
  __shared__ __align__(16) char sm[15360];
  int blk = blockIdx.x, tid = threadIdx.x;
  if (blk < 256) reduce1_body(blk, tid, pws, in1_w, in1_b, scsh, t2red);
  else           kern_part_body(blk - 256, tid, sm, g, pd2);
}

// ---------------- apply IN1+PReLU body (NHWC bf16 transpose out) ----------------
__device__ __forceinline__ void apply1_body(
    int blk, int tid,
    const float* __restrict__ red, const float* __restrict__ scsh,
    const float* __restrict__ alpha_p, ushort* __restrict__ outh)
{
  int cg = blk & 3;
  int pc = (blk >> 2) % 36;
  int b  = blk / (4 * 36);
  int c0 = cg * 32, pix0 = pc * 64;
  float a = *alpha_p;
  __shared__ float lt[32][65];
#pragma unroll
  for (int r = 0; r < 8; r++) {
    int c_l = r * 4 + (tid >> 6), px = tid & 63;
    float x = red[((size_t)b * CO + c0 + c_l) * NPIX1 + pix0 + px];
    float sc = scsh[2 * (b * CO + c0 + c_l)];
    float sh = scsh[2 * (b * CO + c0 + c_l) + 1];
    float o = x * sc + sh;
    lt[c_l][px] = (o >= 0.f) ? o : a * o;
  }
  __syncthreads();
  int c_l = tid & 31;
#pragma unroll
  for (int r = 0; r < 8; r++) {
    int px = r * 8 + (tid >> 5);
    outh[((size_t)b * NPIX1 + pix0 + px) * CO + c0 + c_l] = f2bf(lt[c_l][px]);
  }
}

// ---------------- kern_fin body ----------------
__device__ __forceinline__ void kern_fin_body(
    int blk, int tid,
    const float* __restrict__ pd2, float* __restrict__ kern)
{
  int tile = blk % 36, b = blk / 36;
  int ty = tile / 6, tx = tile % 6;
  int h0 = ty * 16, w0 = tx * 16;
  int px = tid & 15, py = tid >> 4;
  const float* ip = pd2 + ((size_t)(b * 36 + tile) * 4 * 25) * 256 + tid;
  float e[25];
  float sum = 0.f;
#pragma unroll
  for (int p = 0; p < 25; p++) {
    float d = 0.f;
#pragma unroll
    for (int s = 0; s < 4; s++) d += ip[(size_t)(s * 25 + p) * 256];
    e[p] = __expf(-0.5f * d);
    sum += e[p];
  }
  float inv = 1.f / sum;
  int pixg = (h0 + py) * W2 + w0 + px;
  float* op = kern + ((size_t)b * NPIX2 + pixg) * 32;
#pragma unroll
  for (int p = 0; p < 25; p++) op[p] = e[p] * inv;
}

// ---------------- MegaC: apply1 (288) | kern_fin (72) ----------------
__global__ __launch_bounds__(256) void megaC_kernel(
    const float* __restrict__ t2red, const float* __restrict__ scsh,
    const float* __restrict__ prelu1_a, ushort* __restrict__ t1h,
    const float* __restrict__ pd2, float* __restrict__ kern)
{
  int blk = blockIdx.x, tid = threadIdx.x;
  if (blk < 288) apply1_body(blk, tid, t2red, scsh, prelu1_a, t1h);
  else           kern_fin_body(blk - 288, tid, pd2, kern);
}

// ---------------- conv2 standalone (o-split, 576 blocks) ----------------
__global__ __launch_bounds__(256, 4) void conv2_kernel(
    const ushort* __restrict__ t1h, const ushort* __restrict__ wt2,
    float* __restrict__ pws)
{
  __shared__ __align__(16) char sm[6912];
  conv3_body<CO>(blockIdx.x, threadIdx.x, sm, t1h, wt2, pws);
}

// ---------------- reduce2 + IN2 + PReLU + residual ----------------
__global__ __launch_bounds__(256) void reduce2_kernel(
    const float* __restrict__ pout, const float* __restrict__ cbias,
    const float* __restrict__ inw, const float* __restrict__ inb,
    const float* __restrict__ alpha_p, const float* __restrict__ radd,
    float* __restrict__ outf)
{
  int bc = blockIdx.x, tid = threadIdx.x, c = bc & 127;
  float bia = cbias[c];
  float v[9];
  float s = 0.f, s2 = 0.f;
#pragma unroll
  for (int i = 0; i < 9; i++) {
    size_t base = (size_t)bc * NPIX1 + tid + i * 256;
    float x = pout[base];
#pragma unroll
    for (int k = 1; k < NS; k++) x += pout[(size_t)k * B * CO * NPIX1 + base];
    x += bia;
    v[i] = x; s += x; s2 += x * x;
  }
#pragma unroll
  for (int off = 32; off > 0; off >>= 1) {
    s  += __shfl_down(s, off);
    s2 += __shfl_down(s2, off);
  }
  __shared__ float rs[4], rs2[4];
  int wid = tid >> 6, lane = tid & 63;
  if (lane == 0) { rs[wid] = s; rs2[wid] = s2; }
  __syncthreads();
  float S  = rs[0] + rs[1] + rs[2] + rs[3];
  float S2 = rs2[0] + rs2[1] + rs2[2] + rs2[3];
  float mean = S * (1.f / NPIX1);
  float var  = S2 * (1.f / NPIX1) - mean * mean;
  float inv  = rsqrtf(var + 1e-5f);
  float sc = inw[c] * inv;
  float sh = inb[c] - mean * sc;
  float a = *alpha_p;
#pragma unroll
  for (int i = 0; i < 9; i++) {
    size_t base = (size_t)bc * NPIX1 + tid + i * 256;
    float o = v[i] * sc + sh;
    o = (o >= 0.f) ? o : a * o;
    outf[base] = o + radd[base];
  }
}

// ---------------- bicubic taps (align_corners=False, a=-0.75, scale 2) ----------------
__device__ inline void bicubic_taps(int i, int n, int* r, float* w)
{
  const float we[4] = {-0.03515625f, 0.26171875f, 0.87890625f, -0.10546875f};
  bool odd = (i & 1);
  int base = (i >> 1) + (odd ? 0 : -1);
#pragma unroll
  for (int q = 0; q < 4; q++) {
    int rr = base + q - 1;
    r[q] = rr < 0 ? 0 : (rr > n - 1 ? n - 1 : rr);
    w[q] = odd ? we[3 - q] : we[q];
  }
}

// ---------------- 2x bicubic upsample, NCHW f32 -> NHWC bf16 via LDS ----------------
__global__ __launch_bounds__(256) void upsample_t_kernel(
    const float* __restrict__ in, ushort* __restrict__ outh)
{
  int blk = blockIdx.x;
  int cg = blk & 3;
  int i  = (blk >> 2) % H2;
  int b  = blk / (4 * H2);
  int c0 = cg * 32;
  int tid = threadIdx.x;

  int rh[4]; float wh[4];
  bicubic_taps(i, H, rh, wh);

  __shared__ float ls[4 * 48 * 33];
  for (int k = 0; k < 24; k++) {
    int q = tid + k * 256;
    int ww = q % 48;
    int a  = (q / 48) & 3;
    int c_l = q / 192;
    ls[(a * 48 + ww) * 33 + c_l] =
        in[((size_t)b * CO + c0 + c_l) * NPIX1 + rh[a] * W + ww];
  }
  __syncthreads();

  int c_l = tid & 31;
#pragma unroll
  for (int rep = 0; rep < 12; rep++) {
    int j = rep * 8 + (tid >> 5);
    int rwj[4]; float wwj[4];
    bicubic_taps(j, W, rwj, wwj);
    float s = 0.f;
#pragma unroll
    for (int a = 0; a < 4; a++) {
      float r = 0.f;
#pragma unroll
      for (int q = 0; q < 4; q++)
        r += wwj[q] * ls[(a * 48 + rwj[q]) * 33 + c_l];
      s += wh[a] * r;
    }
    outh[((size_t)(b * H2 + i) * W2 + j) * CO + c0 + c_l] = f2bf(s);
  }
}

// ---------------- PAC conv via MFMA: 4-row tile, 3 blocks/CU ----------------
// tile = 4 rows x 16 cols, 64 o; 4 waves = 16 o each (nf=4, ratio 4:1)
// grid: B * 24 * 6 * 2 = 576 ; LDS 48 KB
__global__ __launch_bounds__(256, 3) void pac_mfma_kernel(
    const ushort* __restrict__ xh,    // NHWC bf16 [b][96][96][128]
    const float* __restrict__ kern,   // [b][9216][32]
    const ushort* __restrict__ wb,    // bf16 [25][128][128]
    const float* __restrict__ bias, float* __restrict__ out)
{
  int blk = blockIdx.x;
  int og = blk & 1;
  int tw = (blk >> 1) % 6;
  int th = (blk >> 1) / 6 % 24;
  int b  = blk / (2 * 6 * 24);
  int h0 = th * 4, w0 = tw * 16;
  int tid = threadIdx.x, lane = tid & 63, wv = tid >> 6;
  int l15 = lane & 15, l4 = (lane >> 4) & 3;

  __shared__ ushort xt[160 * 128];  // 8 halo rows x 20 cols x 128 c (40 KB)
  __shared__ float kt[64][33];      // 64 px x 32 taps (8.4 KB)

  for (int q = tid; q < 2560; q += 256) {
    int pixi = q >> 4, cb = q & 15;
    int rh = pixi / 20, rw = pixi - rh * 20;
    int hg = h0 - 2 + rh, wg = w0 - 2 + rw;
    uint4 v{0u, 0u, 0u, 0u};
    if (hg >= 0 && hg < H2 && wg >= 0 && wg < W2)
      v = *(const uint4*)(xh + ((((size_t)b * H2 + hg) * W2 + wg) << 7) + (cb << 3));
    *(uint4*)(xt + (pixi << 7) + ((cb ^ (pixi & 15)) << 3)) = v;
  }
  for (int q = tid; q < 512; q += 256) {
    int pixl = q >> 3, poff = (q & 7) << 2;
    int r = pixl >> 4, col = pixl & 15;
    const float* kp = kern + ((size_t)b * NPIX2 + (h0 + r) * W2 + w0 + col) * 32 + poff;
    float4 kv = *(const float4*)kp;
    kt[pixl][poff] = kv.x; kt[pixl][poff + 1] = kv.y;
    kt[pixl][poff + 2] = kv.z; kt[pixl][poff + 3] = kv.w;
  }
  __syncthreads();

  int wo = og * 64 + wv * 16;     // this wave's 16 output channels
  const ushort* wbase = wb + (size_t)(wo + l15) * CO + l4 * 8;

  f32x4 acc[4];
#pragma unroll
  for (int nf = 0; nf < 4; nf++) acc[nf] = {0.f, 0.f, 0.f, 0.f};

  bf16x8 aC[4], aN[4];
#pragma unroll
  for (int kc = 0; kc < 4; kc++)
    aC[kc] = *(const bf16x8*)(wbase + kc * 32);

  int dy = 0, dx = 0;
#pragma unroll 1
  for (int p = 0; p < 25; ++p) {
    if (p < 24) {
      const ushort* wnext = wbase + (size_t)(p + 1) * CO * CO;
#pragma unroll
      for (int kc = 0; kc < 4; kc++)
        aN[kc] = *(const bf16x8*)(wnext + kc * 32);
    }
#pragma unroll
    for (int nf = 0; nf < 4; nf++) {
      int pix = (nf + dy) * 20 + dx + l15;
      int base = pix << 7;
      int sw = pix & 15;
      f32x4 y = {0.f, 0.f, 0.f, 0.f};
#pragma unroll
      for (int kc = 0; kc < 4; kc++) {
        bf16x8 bb = *(const bf16x8*)(xt + base + (((kc * 4 + l4) ^ sw) << 3));
        y = __builtin_amdgcn_mfma_f32_16x16x32_bf16(aC[kc], bb, y, 0, 0, 0);
      }
      float ks = kt[(nf << 4) + l15][p];
#pragma unroll
      for (int r = 0; r < 4; r++) acc[nf][r] += ks * y[r];
    }
#pragma unroll
    for (int kc = 0; kc < 4; kc++) aC[kc] = aN[kc];
    if (++dx == 5) { dx = 0; dy++; }
  }

#pragma unroll
  for (int nf = 0; nf < 4; nf++) {
    int gpix = (h0 + nf) * W2 + w0 + l15;
#pragma unroll
    for (int r = 0; r < 4; r++) {
      int o = wo + l4 * 4 + r;
      out[((size_t)b * CO + o) * NPIX2 + gpix] = acc[nf][r] + bias[o];
    }
  }
}

extern "C" void kernel_launch(void* const* d_in, const int* in_sizes, int n_in,
                              void* d_out, int out_size, void* d_ws, size_t ws_size,
                              hipStream_t stream)
{
  (void)in_sizes; (void)n_in; (void)out_size; (void)ws_size;
  const float* input    = (const float*)d_in[0];
  const float* feature  = (const float*)d_in[1];
  const float* conv1_w  = (const float*)d_in[2];
  const float* conv1_b  = (const float*)d_in[3];
  const float* in1_w    = (const float*)d_in[4];
  const float* in1_b    = (const float*)d_in[5];
  const float* prelu1_a = (const float*)d_in[6];
  const float* conv2_w  = (const float*)d_in[7];
  const float* conv2_b  = (const float*)d_in[8];
  const float* in2_w    = (const float*)d_in[9];
  const float* in2_b    = (const float*)d_in[10];
  const float* prelu2_a = (const float*)d_in[11];
  const float* res_w    = (const float*)d_in[12];
  const float* res_b    = (const float*)d_in[13];
  const float* feat_w   = (const float*)d_in[14];
  const float* feat_b   = (const float*)d_in[15];
  const float* pac_w    = (const float*)d_in[16];
  const float* pac_b    = (const float*)d_in[17];
  float* out = (float*)d_out;

  // workspace layout (f32 element offsets); all regions DISJOINT
  float* ws = (float*)d_ws;
  ushort* t1h  = (ushort*)ws;                     // 294912 f region
  ushort* wt2  = (ushort*)(ws + 294912);          // 73728 f
  ushort* wt1  = (ushort*)(ws + 368640);          // 147456 f
  float*  t2   = ws + 589824;                     // 589824
  float*  pws  = ws + 1179648;                    // 2359296
  float*  g    = ws + 3538944;                    // 2359296
  ushort* yh   = (ushort*)(ws + 5898240);         // 2359296 ushort
  ushort* wbb  = (ushort*)(ws + 7077888);         // 409600 ushort
  float*  scsh = ws + 7282688;                    // 512 f
  ushort* fh   = (ushort*)(ws + 7283200);         // 2359296 ushort
  ushort* fwb  = (ushort*)(ws + 8462848);         // 16384 ushort
  ushort* wrb  = (ushort*)(ws + 8471040);         // 32768 ushort
  float*  radd = ws + 8487424;                    // 589824 f
  float*  pd2  = ws + 9077248;                    // 1843200 f
  ushort* xinh = (ushort*)(ws + 10920448);        // 294912 f region
  float*  kern = ws + 11215360;                   // 589824 f (end ~47.2 MB)

  // prep: weights + layout transforms (one launch)
  prep_all_kernel<<<5248, 256, 0, stream>>>(
      pac_w, conv1_w, conv2_w, feat_w, res_w, input, feature,
      wbb, wt1, wt2, fwb, wrb, xinh, fh);
  // MegaA: conv1 partials | residual gemm | guidance gemm
  megaA_kernel<<<1008, 256, 0, stream>>>(
      xinh, wt1, pws, wrb, res_b, radd, fh, fwb, feat_b, g);
  // MegaB: reduce1+stats | gaussian d2 partials
  megaB_kernel<<<544, 256, 0, stream>>>(pws, in1_w, in1_b, scsh, t2, g, pd2);
  // MegaC: apply IN1+PReLU | kern finalize
  megaC_kernel<<<360, 256, 0, stream>>>(t2, scsh, prelu1_a, t1h, pd2, kern);
  // conv2 partials (o-split, 576 blocks)
  conv2_kernel<<<576, 256, 0, stream>>>(t1h, wt2, pws);
  // reduce2 + IN2 + PReLU + residual
  reduce2_kernel<<<B * CO, 256, 0, stream>>>(
      pws, conv2_b, in2_w, in2_b, prelu2_a, radd, t2);
  // bicubic 2x upsample -> NHWC bf16
  upsample_t_kernel<<<B * H2 * 4, 256, 0, stream>>>(t2, yh);
  // PAC conv on matrix cores (4-row tile, grid 576, 3 blocks/CU)
  pac_mfma_kernel<<<B * 24 * 6 * 2, 256, 0, stream>>>(yh, kern, wbb, pac_b, out);
}

// Round 20
// 121.399 us; speedup vs baseline: 1.0424x; 1.0424x over previous
//
#include <hip/hip_runtime.h>
#include <hip/hip_bf16.h>

typedef __attribute__((ext_vector_type(8))) short bf16x8;
typedef __attribute__((ext_vector_type(4))) float f32x4;

constexpr int B   = 2;
constexpr int CIN = 256;
constexpr int CO  = 128;
constexpr int H = 48, W = 48;
constexpr int H2 = 96, W2 = 96;
constexpr int NPIX1 = H * W;    // 2304
constexpr int NPIX2 = H2 * W2;  // 9216
constexpr int NS = 4;           // conv split-K factor

__device__ inline ushort f2bf(float v)
{
  __hip_bfloat16 h = __float2bfloat16(v);
  return *reinterpret_cast<ushort*>(&h);
}

// ---------------- prep: all weight transforms + input/feature NHWC cvt ----------------
__global__ __launch_bounds__(256) void prep_all_kernel(
    const float* __restrict__ pac_w, const float* __restrict__ conv1_w,
    const float* __restrict__ conv2_w, const float* __restrict__ feat_w,
    const float* __restrict__ res_w, const float* __restrict__ input,
    const float* __restrict__ feature,
    ushort* __restrict__ wbb, ushort* __restrict__ wt1, ushort* __restrict__ wt2,
    ushort* __restrict__ fwb, ushort* __restrict__ wrb,
    ushort* __restrict__ xinh, ushort* __restrict__ fh)
{
  __shared__ float lt[32][65];
  int blk = blockIdx.x, tid = threadIdx.x;
  if (blk < 1600) {
    int idx = blk * 256 + tid;
    int c = idx & 127, o = (idx >> 7) & 127, p = idx >> 14;
    wbb[idx] = f2bf(pac_w[((size_t)o * CO + c) * 25 + p]);
  } else if (blk < 2752) {
    int idx = (blk - 1600) * 256 + tid;
    int ci = idx & 255, o = (idx >> 8) & 127, tap = idx >> 15;
    wt1[idx] = f2bf(conv1_w[((size_t)o * CIN + ci) * 9 + tap]);
  } else if (blk < 3328) {
    int idx = (blk - 2752) * 256 + tid;
    int ci = idx & 127, o = (idx >> 7) & 127, tap = idx >> 14;
    wt2[idx] = f2bf(conv2_w[((size_t)o * CO + ci) * 9 + tap]);
  } else if (blk < 3392) {
    int idx = (blk - 3328) * 256 + tid;
    fwb[idx] = f2bf(feat_w[idx]);
  } else if (blk < 3520) {
    int idx = (blk - 3392) * 256 + tid;
    wrb[idx] = f2bf(res_w[idx]);
  } else if (blk < 4096) {
    int b2 = blk - 3520;
    int cg = b2 & 7;
    int pc = (b2 >> 3) % 36;
    int b  = b2 / (8 * 36);
    int c0 = cg * 32, pix0 = pc * 64;
#pragma unroll
    for (int r = 0; r < 8; r++) {
      int c_l = r * 4 + (tid >> 6), px = tid & 63;
      lt[c_l][px] = input[((size_t)b * CIN + c0 + c_l) * NPIX1 + pix0 + px];
    }
    __syncthreads();
    int c_l = tid & 31;
#pragma unroll
    for (int r = 0; r < 8; r++) {
      int px = r * 8 + (tid >> 5);
      xinh[((size_t)b * NPIX1 + pix0 + px) * CIN + c0 + c_l] = f2bf(lt[c_l][px]);
    }
  } else {
    int b2 = blk - 4096;
    int cg = b2 & 3;
    int pc = (b2 >> 2) % 144;
    int b  = b2 / (4 * 144);
    int c0 = cg * 32, pix0 = pc * 64;
#pragma unroll
    for (int r = 0; r < 8; r++) {
      int c_l = r * 4 + (tid >> 6), px = tid & 63;
      lt[c_l][px] = feature[((size_t)b * CO + c0 + c_l) * NPIX2 + pix0 + px];
    }
    __syncthreads();
    int c_l = tid & 31;
#pragma unroll
    for (int r = 0; r < 8; r++) {
      int px = r * 8 + (tid >> 5);
      fh[((size_t)b * NPIX2 + pix0 + px) * CO + c0 + c_l] = f2bf(lt[c_l][px]);
    }
  }
}

// ---------------- conv3x3 MFMA body, split-K (NS) x split-O (2) ----------------
template<int CIg>
__device__ __forceinline__ void conv3_body(
    int blk, int tid, char* smraw,
    const ushort* __restrict__ xh, const ushort* __restrict__ wt,
    float* __restrict__ pout)
{
  constexpr int CS = CIg / NS;
  constexpr int G  = CS / 8;
  constexpr int KC = CS / 32;
  ushort* xt = (ushort*)smraw;
  int tile = blk % 36;
  int s = (blk / 36) & 3;
  int oh = (blk / 144) & 1;
  int b = blk / 288;
  int th = tile / 3, tw = tile % 3;
  int h0 = th * 4, w0 = tw * 16;
  int lane = tid & 63, wv = tid >> 6;
  int l15 = lane & 15, l4 = (lane >> 4) & 3;

  for (int q = tid; q < 108 * G; q += 256) {
    int pixi = q / G, g = q & (G - 1);
    int rh = pixi / 18, rw = pixi - rh * 18;
    int hg = h0 - 1 + rh, wg = w0 - 1 + rw;
    uint4 v{0u, 0u, 0u, 0u};
    if (hg >= 0 && hg < H && wg >= 0 && wg < W)
      v = *(const uint4*)(xh + (size_t)(b * NPIX1 + hg * W + wg) * CIg + s * CS + g * 8);
    *(uint4*)(xt + pixi * CS + ((g ^ (pixi & (G - 1))) * 8)) = v;
  }
  __syncthreads();

  int wo = oh * 64 + wv * 16;
  const ushort* wbase = wt + (size_t)(wo + l15) * CIg + s * CS + l4 * 8;

  f32x4 acc[4];
#pragma unroll
  for (int nf = 0; nf < 4; nf++) acc[nf] = {0.f, 0.f, 0.f, 0.f};

  bf16x8 aC[KC], aN[KC];
#pragma unroll
  for (int kc = 0; kc < KC; kc++)
    aC[kc] = *(const bf16x8*)(wbase + kc * 32);

#pragma unroll 1
  for (int tap = 0; tap < 9; ++tap) {
    if (tap < 8) {
      const ushort* wn = wbase + (size_t)(tap + 1) * 128 * CIg;
#pragma unroll
      for (int kc = 0; kc < KC; kc++)
        aN[kc] = *(const bf16x8*)(wn + kc * 32);
    }
    int kh = (tap >= 6) ? 2 : ((tap >= 3) ? 1 : 0);
    int kw = tap - kh * 3;
#pragma unroll
    for (int kc = 0; kc < KC; kc++) {
#pragma unroll
      for (int nf = 0; nf < 4; nf++) {
        int pix = (nf + kh) * 18 + kw + l15;
        bf16x8 bb = *(const bf16x8*)(xt + pix * CS + (((kc * 4 + l4) ^ (pix & (G - 1))) * 8));
        acc[nf] = __builtin_amdgcn_mfma_f32_16x16x32_bf16(aC[kc], bb, acc[nf], 0, 0, 0);
      }
    }
#pragma unroll
    for (int kc = 0; kc < KC; kc++) aC[kc] = aN[kc];
  }

#pragma unroll
  for (int nf = 0; nf < 4; nf++) {
    int pixg = (h0 + nf) * W + w0 + l15;
#pragma unroll
    for (int r = 0; r < 4; r++) {
      int o = wo + l4 * 4 + r;
      pout[((size_t)(s * B + b) * CO + o) * NPIX1 + pixg] = acc[nf][r];
    }
  }
}

// ---------------- gemm_res body (32 px, CI=256) ----------------
__device__ __forceinline__ void gemm_res_body(
    int blk, int tid, char* smraw,
    const ushort* __restrict__ xh, const ushort* __restrict__ wrb,
    const float* __restrict__ bias, float* __restrict__ out)
{
  ushort* xt = (ushort*)smraw;    // 32*256
  int pc = blk % 72;
  int b  = blk / 72;
  int pix0 = pc * 32;
  int lane = tid & 63, wv = tid >> 6;
  int l15 = lane & 15, l4 = (lane >> 4) & 3;

  for (int q = tid; q < 1024; q += 256) {
    int pixi = q >> 5, g = q & 31;
    uint4 v = *(const uint4*)(xh + (((size_t)b * NPIX1 + pix0 + pixi) << 8) + (g << 3));
    *(uint4*)(xt + (pixi << 8) + ((g ^ (pixi & 31)) << 3)) = v;
  }
  __syncthreads();

  int wo = wv * 32;
  const ushort* wbase = wrb + (size_t)(wo + l15) * CIN + l4 * 8;
  bf16x8 a0[8], a1[8];
#pragma unroll
  for (int kc = 0; kc < 8; kc++) {
    a0[kc] = *(const bf16x8*)(wbase + kc * 32);
    a1[kc] = *(const bf16x8*)(wbase + 16 * CIN + kc * 32);
  }
  f32x4 acc0[2], acc1[2];
#pragma unroll
  for (int nf = 0; nf < 2; nf++) {
    acc0[nf] = {0.f, 0.f, 0.f, 0.f};
    acc1[nf] = {0.f, 0.f, 0.f, 0.f};
  }
#pragma unroll
  for (int nf = 0; nf < 2; nf++) {
    int pix = nf * 16 + l15;
    int base = pix << 8;
    int sw = pix & 31;
#pragma unroll
    for (int kc = 0; kc < 8; kc++) {
      bf16x8 bb = *(const bf16x8*)(xt + base + ((((kc << 2) + l4) ^ sw) << 3));
      acc0[nf] = __builtin_amdgcn_mfma_f32_16x16x32_bf16(a0[kc], bb, acc0[nf], 0, 0, 0);
      acc1[nf] = __builtin_amdgcn_mfma_f32_16x16x32_bf16(a1[kc], bb, acc1[nf], 0, 0, 0);
    }
  }
#pragma unroll
  for (int nf = 0; nf < 2; nf++) {
    int gp = pix0 + nf * 16 + l15;
#pragma unroll
    for (int r = 0; r < 4; r++) {
      int o = wo + l4 * 4 + r;
      out[((size_t)b * CO + o) * NPIX1 + gp] = acc0[nf][r] + bias[o];
      out[((size_t)b * CO + o + 16) * NPIX1 + gp] = acc1[nf][r] + bias[o + 16];
    }
  }
}

// ---------------- gemm1x1 body (64 px, CI=128) ----------------
__device__ __forceinline__ void gemm1x1_body(
    int blk, int tid, char* smraw,
    const ushort* __restrict__ fh, const ushort* __restrict__ fwb,
    const float* __restrict__ bias, float* __restrict__ out)
{
  ushort* xt = (ushort*)smraw;    // 64*128
  int pc = blk % 144;
  int b  = blk / 144;
  int pix0 = pc * 64;
  int lane = tid & 63, wv = tid >> 6;
  int l15 = lane & 15, l4 = (lane >> 4) & 3;

  for (int q = tid; q < 1024; q += 256) {
    int pixi = q >> 4, g = q & 15;
    uint4 v = *(const uint4*)(fh + (((size_t)b * NPIX2 + pix0 + pixi) << 7) + (g << 3));
    *(uint4*)(xt + (pixi << 7) + ((g ^ (pixi & 15)) << 3)) = v;
  }
  __syncthreads();

  int wo = wv * 32;
  const ushort* wbase = fwb + (size_t)(wo + l15) * CO + l4 * 8;
  bf16x8 a0[4], a1[4];
#pragma unroll
  for (int kc = 0; kc < 4; kc++) {
    a0[kc] = *(const bf16x8*)(wbase + kc * 32);
    a1[kc] = *(const bf16x8*)(wbase + 16 * CO + kc * 32);
  }
  f32x4 acc0[4], acc1[4];
#pragma unroll
  for (int nf = 0; nf < 4; nf++) {
    acc0[nf] = {0.f, 0.f, 0.f, 0.f};
    acc1[nf] = {0.f, 0.f, 0.f, 0.f};
  }
#pragma unroll
  for (int nf = 0; nf < 4; nf++) {
    int pix = nf * 16 + l15;
    int base = pix << 7;
    int sw = pix & 15;
#pragma unroll
    for (int kc = 0; kc < 4; kc++) {
      bf16x8 bb = *(const bf16x8*)(xt + base + ((((kc << 2) + l4) ^ sw) << 3));
      acc0[nf] = __builtin_amdgcn_mfma_f32_16x16x32_bf16(a0[kc], bb, acc0[nf], 0, 0, 0);
      acc1[nf] = __builtin_amdgcn_mfma_f32_16x16x32_bf16(a1[kc], bb, acc1[nf], 0, 0, 0);
    }
  }
#pragma unroll
  for (int nf = 0; nf < 4; nf++) {
    int gp = pix0 + nf * 16 + l15;
#pragma unroll
    for (int r = 0; r < 4; r++) {
      int o = wo + l4 * 4 + r;
      out[((size_t)b * CO + o) * NPIX2 + gp] = acc0[nf][r] + bias[o];
      out[((size_t)b * CO + o + 16) * NPIX2 + gp] = acc1[nf][r] + bias[o + 16];
    }
  }
}

// ---------------- MegaA: conv1 (576) | gemm_res (144) | gemm1x1 (288) ----------------
__global__ __launch_bounds__(256, 4) void megaA_kernel(
    const ushort* __restrict__ xinh, const ushort* __restrict__ wt1,
    float* __restrict__ pws,
    const ushort* __restrict__ wrb, const float* __restrict__ res_b,
    float* __restrict__ radd,
    const ushort* __restrict__ fh, const ushort* __restrict__ fwb,
    const float* __restrict__ feat_b, float* __restrict__ g)
{
  __shared__ __align__(16) char sm[16384];
  int blk = blockIdx.x, tid = threadIdx.x;
  if (blk < 576)      conv3_body<CIN>(blk, tid, sm, xinh, wt1, pws);
  else if (blk < 720) gemm_res_body(blk - 576, tid, sm, xinh, wrb, res_b, radd);
  else                gemm1x1_body(blk - 720, tid, sm, fh, fwb, feat_b, g);
}

// ---------------- reduce1 + stats body ----------------
__device__ __forceinline__ void reduce1_body(
    int bc, int tid,
    const float* __restrict__ pout, const float* __restrict__ inw,
    const float* __restrict__ inb, float* __restrict__ scsh,
    float* __restrict__ outred)
{
  int c = bc & 127;
  float s = 0.f, s2 = 0.f;
#pragma unroll
  for (int i = 0; i < 9; i++) {
    size_t base = (size_t)bc * NPIX1 + tid + i * 256;
    float x = pout[base];
#pragma unroll
    for (int k = 1; k < NS; k++) x += pout[(size_t)k * B * CO * NPIX1 + base];
    outred[base] = x;
    s += x; s2 += x * x;
  }
#pragma unroll
  for (int off = 32; off > 0; off >>= 1) {
    s  += __shfl_down(s, off);
    s2 += __shfl_down(s2, off);
  }
  __shared__ float rs[4], rs2[4];
  int wid = tid >> 6, lane = tid & 63;
  if (lane == 0) { rs[wid] = s; rs2[wid] = s2; }
  __syncthreads();
  if (tid == 0) {
    float S  = rs[0] + rs[1] + rs[2] + rs[3];
    float S2 = rs2[0] + rs2[1] + rs2[2] + rs2[3];
    float mean = S * (1.f / NPIX1);
    float var  = S2 * (1.f / NPIX1) - mean * mean;
    float inv  = rsqrtf(var + 1e-5f);
    float sc = inw[c] * inv;
    scsh[2 * bc]     = sc;
    scsh[2 * bc + 1] = inb[c] - mean * sc;
  }
}

// ---------------- PAC guidance d2 partial body (8-ch chunks) ----------------
__device__ __forceinline__ void kern_part_body(
    int blk, int tid, char* smraw,
    const float* __restrict__ g, float* __restrict__ pd2)
{
  float (*gt)[480] = (float(*)[480])smraw;
  int s = blk & 3;
  int tile = (blk >> 2) % 36;
  int b = blk / (4 * 36);
  int ty = tile / 6, tx = tile % 6;
  int h0 = ty * 16, w0 = tx * 16;
  int px = tid & 15, py = tid >> 4;
  float d2[25];
#pragma unroll
  for (int p = 0; p < 25; p++) d2[p] = 0.f;

  int cbase = s * 32;
#pragma unroll 1
  for (int cc = 0; cc < 32; cc += 8) {
    for (int idx = tid; idx < 3200; idx += 256) {
      int c_l = idx / 400, r = idx - c_l * 400;
      int rh = r / 20, rw = r - rh * 20;
      int hh = h0 - 2 + rh, ww = w0 - 2 + rw;
      float v = 0.f;
      if (hh >= 0 && hh < H2 && ww >= 0 && ww < W2)
        v = g[((size_t)b * CO + cbase + cc + c_l) * NPIX2 + hh * W2 + ww];
      gt[c_l][rh * 24 + rw] = v;
    }
    __syncthreads();
#pragma unroll
    for (int c_l = 0; c_l < 8; c_l++) {
      float ctr = gt[c_l][(py + 2) * 24 + px + 2];
#pragma unroll
      for (int dy = 0; dy < 5; dy++)
#pragma unroll
        for (int dx = 0; dx < 5; dx++) {
          float d = gt[c_l][(py + dy) * 24 + px + dx] - ctr;
          d2[dy * 5 + dx] += d * d;
        }
    }
    __syncthreads();
  }
  float* op = pd2 + ((size_t)((b * 36 + tile) * 4 + s) * 25) * 256 + tid;
#pragma unroll
  for (int p = 0; p < 25; p++) op[(size_t)p * 256] = d2[p];
}

// ---------------- MegaB: reduce1 (256) | kern_part (288) ----------------
__global__ __launch_bounds__(256, 4) void megaB_kernel(
    const float* __restrict__ pws, const float* __restrict__ in1_w,
    const float* __restrict__ in1_b, float* __restrict__ scsh,
    float* __restrict__ t2red,
    const float* __restrict__ g, float* __restrict__ pd2)
{
  __shared__ __align__(16) char sm[15360];
  int blk = blockIdx.x, tid = threadIdx.x;
  if (blk < 256) reduce1_body(blk, tid, pws, in1_w, in1_b, scsh, t2red);
  else           kern_part_body(blk - 256, tid, sm, g, pd2);
}

// ---------------- apply IN1+PReLU body (NHWC bf16 transpose out) ----------------
__device__ __forceinline__ void apply1_body(
    int blk, int tid,
    const float* __restrict__ red, const float* __restrict__ scsh,
    const float* __restrict__ alpha_p, ushort* __restrict__ outh)
{
  int cg = blk & 3;
  int pc = (blk >> 2) % 36;
  int b  = blk / (4 * 36);
  int c0 = cg * 32, pix0 = pc * 64;
  float a = *alpha_p;
  __shared__ float lt[32][65];
#pragma unroll
  for (int r = 0; r < 8; r++) {
    int c_l = r * 4 + (tid >> 6), px = tid & 63;
    float x = red[((size_t)b * CO + c0 + c_l) * NPIX1 + pix0 + px];
    float sc = scsh[2 * (b * CO + c0 + c_l)];
    float sh = scsh[2 * (b * CO + c0 + c_l) + 1];
    float o = x * sc + sh;
    lt[c_l][px] = (o >= 0.f) ? o : a * o;
  }
  __syncthreads();
  int c_l = tid & 31;
#pragma unroll
  for (int r = 0; r < 8; r++) {
    int px = r * 8 + (tid >> 5);
    outh[((size_t)b * NPIX1 + pix0 + px) * CO + c0 + c_l] = f2bf(lt[c_l][px]);
  }
}

// ---------------- kern_fin body ----------------
__device__ __forceinline__ void kern_fin_body(
    int blk, int tid,
    const float* __restrict__ pd2, float* __restrict__ kern)
{
  int tile = blk % 36, b = blk / 36;
  int ty = tile / 6, tx = tile % 6;
  int h0 = ty * 16, w0 = tx * 16;
  int px = tid & 15, py = tid >> 4;
  const float* ip = pd2 + ((size_t)(b * 36 + tile) * 4 * 25) * 256 + tid;
  float e[25];
  float sum = 0.f;
#pragma unroll
  for (int p = 0; p < 25; p++) {
    float d = 0.f;
#pragma unroll
    for (int s = 0; s < 4; s++) d += ip[(size_t)(s * 25 + p) * 256];
    e[p] = __expf(-0.5f * d);
    sum += e[p];
  }
  float inv = 1.f / sum;
  int pixg = (h0 + py) * W2 + w0 + px;
  float* op = kern + ((size_t)b * NPIX2 + pixg) * 32;
#pragma unroll
  for (int p = 0; p < 25; p++) op[p] = e[p] * inv;
}

// ---------------- MegaC: apply1 (288) | kern_fin (72) ----------------
__global__ __launch_bounds__(256) void megaC_kernel(
    const float* __restrict__ t2red, const float* __restrict__ scsh,
    const float* __restrict__ prelu1_a, ushort* __restrict__ t1h,
    const float* __restrict__ pd2, float* __restrict__ kern)
{
  int blk = blockIdx.x, tid = threadIdx.x;
  if (blk < 288) apply1_body(blk, tid, t2red, scsh, prelu1_a, t1h);
  else           kern_fin_body(blk - 288, tid, pd2, kern);
}

// ---------------- conv2 standalone (o-split, 576 blocks) ----------------
__global__ __launch_bounds__(256, 4) void conv2_kernel(
    const ushort* __restrict__ t1h, const ushort* __restrict__ wt2,
    float* __restrict__ pws)
{
  __shared__ __align__(16) char sm[6912];
  conv3_body<CO>(blockIdx.x, threadIdx.x, sm, t1h, wt2, pws);
}

// ---------------- reduce2 + IN2 + PReLU + residual ----------------
__global__ __launch_bounds__(256) void reduce2_kernel(
    const float* __restrict__ pout, const float* __restrict__ cbias,
    const float* __restrict__ inw, const float* __restrict__ inb,
    const float* __restrict__ alpha_p, const float* __restrict__ radd,
    float* __restrict__ outf)
{
  int bc = blockIdx.x, tid = threadIdx.x, c = bc & 127;
  float bia = cbias[c];
  float v[9];
  float s = 0.f, s2 = 0.f;
#pragma unroll
  for (int i = 0; i < 9; i++) {
    size_t base = (size_t)bc * NPIX1 + tid + i * 256;
    float x = pout[base];
#pragma unroll
    for (int k = 1; k < NS; k++) x += pout[(size_t)k * B * CO * NPIX1 + base];
    x += bia;
    v[i] = x; s += x; s2 += x * x;
  }
#pragma unroll
  for (int off = 32; off > 0; off >>= 1) {
    s  += __shfl_down(s, off);
    s2 += __shfl_down(s2, off);
  }
  __shared__ float rs[4], rs2[4];
  int wid = tid >> 6, lane = tid & 63;
  if (lane == 0) { rs[wid] = s; rs2[wid] = s2; }
  __syncthreads();
  float S  = rs[0] + rs[1] + rs[2] + rs[3];
  float S2 = rs2[0] + rs2[1] + rs2[2] + rs2[3];
  float mean = S * (1.f / NPIX1);
  float var  = S2 * (1.f / NPIX1) - mean * mean;
  float inv  = rsqrtf(var + 1e-5f);
  float sc = inw[c] * inv;
  float sh = inb[c] - mean * sc;
  float a = *alpha_p;
#pragma unroll
  for (int i = 0; i < 9; i++) {
    size_t base = (size_t)bc * NPIX1 + tid + i * 256;
    float o = v[i] * sc + sh;
    o = (o >= 0.f) ? o : a * o;
    outf[base] = o + radd[base];
  }
}

// ---------------- bicubic taps (align_corners=False, a=-0.75, scale 2) ----------------
__device__ inline void bicubic_taps(int i, int n, int* r, float* w)
{
  const float we[4] = {-0.03515625f, 0.26171875f, 0.87890625f, -0.10546875f};
  bool odd = (i & 1);
  int base = (i >> 1) + (odd ? 0 : -1);
#pragma unroll
  for (int q = 0; q < 4; q++) {
    int rr = base + q - 1;
    r[q] = rr < 0 ? 0 : (rr > n - 1 ? n - 1 : rr);
    w[q] = odd ? we[3 - q] : we[q];
  }
}

// ---------------- 2x bicubic upsample, NCHW f32 -> NHWC bf16 via LDS ----------------
__global__ __launch_bounds__(256) void upsample_t_kernel(
    const float* __restrict__ in, ushort* __restrict__ outh)
{
  int blk = blockIdx.x;
  int cg = blk & 3;
  int i  = (blk >> 2) % H2;
  int b  = blk / (4 * H2);
  int c0 = cg * 32;
  int tid = threadIdx.x;

  int rh[4]; float wh[4];
  bicubic_taps(i, H, rh, wh);

  __shared__ float ls[4 * 48 * 33];
  for (int k = 0; k < 24; k++) {
    int q = tid + k * 256;
    int ww = q % 48;
    int a  = (q / 48) & 3;
    int c_l = q / 192;
    ls[(a * 48 + ww) * 33 + c_l] =
        in[((size_t)b * CO + c0 + c_l) * NPIX1 + rh[a] * W + ww];
  }
  __syncthreads();

  int c_l = tid & 31;
#pragma unroll
  for (int rep = 0; rep < 12; rep++) {
    int j = rep * 8 + (tid >> 5);
    int rwj[4]; float wwj[4];
    bicubic_taps(j, W, rwj, wwj);
    float s = 0.f;
#pragma unroll
    for (int a = 0; a < 4; a++) {
      float r = 0.f;
#pragma unroll
      for (int q = 0; q < 4; q++)
        r += wwj[q] * ls[(a * 48 + rwj[q]) * 33 + c_l];
      s += wh[a] * r;
    }
    outh[((size_t)(b * H2 + i) * W2 + j) * CO + c0 + c_l] = f2bf(s);
  }
}

// ---------------- PAC conv via MFMA (R8-proven config: 8-row tile, grid 288) ----------------
__global__ __launch_bounds__(256, 2) void pac_mfma_kernel(
    const ushort* __restrict__ xh,    // NHWC bf16 [b][96][96][128]
    const float* __restrict__ kern,   // [b][9216][32]
    const ushort* __restrict__ wb,    // bf16 [25][128][128]
    const float* __restrict__ bias, float* __restrict__ out)
{
  int blk = blockIdx.x;
  int og = blk & 1;
  int tw = (blk >> 1) % 6;
  int th = (blk >> 1) / 6 % 12;
  int b  = blk / (2 * 6 * 12);
  int h0 = th * 8, w0 = tw * 16;
  int tid = threadIdx.x, lane = tid & 63, wv = tid >> 6;
  int l15 = lane & 15, l4 = (lane >> 4) & 3;

  __shared__ ushort xt[240 * 128];
  __shared__ float kt[128][33];

  for (int q = tid; q < 3840; q += 256) {
    int pixi = q >> 4, cb = q & 15;
    int rh = pixi / 20, rw = pixi - rh * 20;
    int hg = h0 - 2 + rh, wg = w0 - 2 + rw;
    uint4 v{0u, 0u, 0u, 0u};
    if (hg >= 0 && hg < H2 && wg >= 0 && wg < W2)
      v = *(const uint4*)(xh + ((((size_t)b * H2 + hg) * W2 + wg) << 7) + (cb << 3));
    *(uint4*)(xt + (pixi << 7) + ((cb ^ (pixi & 15)) << 3)) = v;
  }
  for (int q = tid; q < 1024; q += 256) {
    int pixl = q >> 3, poff = (q & 7) << 2;
    int r = pixl >> 4, col = pixl & 15;
    const float* kp = kern + ((size_t)b * NPIX2 + (h0 + r) * W2 + w0 + col) * 32 + poff;
    float4 kv = *(const float4*)kp;
    kt[pixl][poff] = kv.x; kt[pixl][poff + 1] = kv.y;
    kt[pixl][poff + 2] = kv.z; kt[pixl][poff + 3] = kv.w;
  }
  __syncthreads();

  int wo = og * 64 + wv * 16;
  const ushort* wbase = wb + (size_t)(wo + l15) * CO + l4 * 8;

  f32x4 acc[8];
#pragma unroll
  for (int nf = 0; nf < 8; nf++) acc[nf] = {0.f, 0.f, 0.f, 0.f};

  bf16x8 aC[4], aN[4];
#pragma unroll
  for (int kc = 0; kc < 4; kc++)
    aC[kc] = *(const bf16x8*)(wbase + kc * 32);

  int dy = 0, dx = 0;
#pragma unroll 1
  for (int p = 0; p < 25; ++p) {
    if (p < 24) {
      const ushort* wnext = wbase + (size_t)(p + 1) * CO * CO;
#pragma unroll
      for (int kc = 0; kc < 4; kc++)
        aN[kc] = *(const bf16x8*)(wnext + kc * 32);
    }
#pragma unroll
    for (int nf = 0; nf < 8; nf++) {
      int pix = (nf + dy) * 20 + dx + l15;
      int base = pix << 7;
      int sw = pix & 15;
      f32x4 y = {0.f, 0.f, 0.f, 0.f};
#pragma unroll
      for (int kc = 0; kc < 4; kc++) {
        bf16x8 bb = *(const bf16x8*)(xt + base + (((kc * 4 + l4) ^ sw) << 3));
        y = __builtin_amdgcn_mfma_f32_16x16x32_bf16(aC[kc], bb, y, 0, 0, 0);
      }
      float ks = kt[(nf << 4) + l15][p];
#pragma unroll
      for (int r = 0; r < 4; r++) acc[nf][r] += ks * y[r];
    }
#pragma unroll
    for (int kc = 0; kc < 4; kc++) aC[kc] = aN[kc];
    if (++dx == 5) { dx = 0; dy++; }
  }

#pragma unroll
  for (int nf = 0; nf < 8; nf++) {
    int gpix = (h0 + nf) * W2 + w0 + l15;
#pragma unroll
    for (int r = 0; r < 4; r++) {
      int o = wo + l4 * 4 + r;
      out[((size_t)b * CO + o) * NPIX2 + gpix] = acc[nf][r] + bias[o];
    }
  }
}

extern "C" void kernel_launch(void* const* d_in, const int* in_sizes, int n_in,
                              void* d_out, int out_size, void* d_ws, size_t ws_size,
                              hipStream_t stream)
{
  (void)in_sizes; (void)n_in; (void)out_size; (void)ws_size;
  const float* input    = (const float*)d_in[0];
  const float* feature  = (const float*)d_in[1];
  const float* conv1_w  = (const float*)d_in[2];
  const float* conv1_b  = (const float*)d_in[3];
  const float* in1_w    = (const float*)d_in[4];
  const float* in1_b    = (const float*)d_in[5];
  const float* prelu1_a = (const float*)d_in[6];
  const float* conv2_w  = (const float*)d_in[7];
  const float* conv2_b  = (const float*)d_in[8];
  const float* in2_w    = (const float*)d_in[9];
  const float* in2_b    = (const float*)d_in[10];
  const float* prelu2_a = (const float*)d_in[11];
  const float* res_w    = (const float*)d_in[12];
  const float* res_b    = (const float*)d_in[13];
  const float* feat_w   = (const float*)d_in[14];
  const float* feat_b   = (const float*)d_in[15];
  const float* pac_w    = (const float*)d_in[16];
  const float* pac_b    = (const float*)d_in[17];
  float* out = (float*)d_out;

  // workspace layout (f32 element offsets); all regions DISJOINT
  float* ws = (float*)d_ws;
  ushort* t1h  = (ushort*)ws;                     // 294912 f region
  ushort* wt2  = (ushort*)(ws + 294912);          // 73728 f
  ushort* wt1  = (ushort*)(ws + 368640);          // 147456 f
  float*  t2   = ws + 589824;                     // 589824
  float*  pws  = ws + 1179648;                    // 2359296
  float*  g    = ws + 3538944;                    // 2359296
  ushort* yh   = (ushort*)(ws + 5898240);         // 2359296 ushort
  ushort* wbb  = (ushort*)(ws + 7077888);         // 409600 ushort
  float*  scsh = ws + 7282688;                    // 512 f
  ushort* fh   = (ushort*)(ws + 7283200);         // 2359296 ushort
  ushort* fwb  = (ushort*)(ws + 8462848);         // 16384 ushort
  ushort* wrb  = (ushort*)(ws + 8471040);         // 32768 ushort
  float*  radd = ws + 8487424;                    // 589824 f
  float*  pd2  = ws + 9077248;                    // 1843200 f
  ushort* xinh = (ushort*)(ws + 10920448);        // 294912 f region
  float*  kern = ws + 11215360;                   // 589824 f (end ~47.2 MB)

  // prep: weights + layout transforms (one launch)
  prep_all_kernel<<<5248, 256, 0, stream>>>(
      pac_w, conv1_w, conv2_w, feat_w, res_w, input, feature,
      wbb, wt1, wt2, fwb, wrb, xinh, fh);
  // MegaA: conv1 partials | residual gemm | guidance gemm
  megaA_kernel<<<1008, 256, 0, stream>>>(
      xinh, wt1, pws, wrb, res_b, radd, fh, fwb, feat_b, g);
  // MegaB: reduce1+stats | gaussian d2 partials
  megaB_kernel<<<544, 256, 0, stream>>>(pws, in1_w, in1_b, scsh, t2, g, pd2);
  // MegaC: apply IN1+PReLU | kern finalize
  megaC_kernel<<<360, 256, 0, stream>>>(t2, scsh, prelu1_a, t1h, pd2, kern);
  // conv2 partials (o-split, 576 blocks)
  conv2_kernel<<<576, 256, 0, stream>>>(t1h, wt2, pws);
  // reduce2 + IN2 + PReLU + residual
  reduce2_kernel<<<B * CO, 256, 0, stream>>>(
      pws, conv2_b, in2_w, in2_b, prelu2_a, radd, t2);
  // bicubic 2x upsample -> NHWC bf16
  upsample_t_kernel<<<B * H2 * 4, 256, 0, stream>>>(t2, yh);
  // PAC conv on matrix cores (R8 config: 8-row tile, grid 288)
  pac_mfma_kernel<<<B * 12 * 6 * 2, 256, 0, stream>>>(yh, kern, wbb, pac_b, out);
}